// Round 3
// baseline (513.239 us; speedup 1.0000x reference)
//
#include <hip/hip_runtime.h>
#include <hip/hip_bf16.h>
#include <cstdint>
#include <cstddef>

typedef __bf16 bf16;
typedef __attribute__((ext_vector_type(8))) __bf16 bf16x8;
typedef __attribute__((ext_vector_type(4))) __bf16 bf16x4;
typedef __attribute__((ext_vector_type(4))) float f32x4;

#define MFMA_BF16(a, b, c) __builtin_amdgcn_mfma_f32_16x16x32_bf16((a), (b), (c), 0, 0, 0)

constexpr int CB = 4;       // batch
constexpr int CS = 2048;    // seq
constexpr int CD = 1024;    // model dim
constexpr int CDA = 1024;   // attn dim
constexpr int CH = 16;      // heads
constexpr int CM = CB * CS; // 8192 rows

// ---------------------------------------------------------------------------
// GEMM: C[M,N] = A[M,K] * W[N,K]^T + bias[N]  (unchanged from round 2)
// ---------------------------------------------------------------------------
template <bool A_BF16, bool OUT_F32>
__global__ __launch_bounds__(256) void gemm_nt_bias(
    const void* __restrict__ Ap, const float* __restrict__ W,
    const float* __restrict__ bias, void* __restrict__ Cp,
    int M, int N, int K)
{
    __shared__ bf16 As[128][72];  // BK=64 + pad 8
    __shared__ bf16 Bs[128][72];

    const int t = threadIdx.x;
    const int lane = t & 63;
    const int wid = t >> 6;
    const int wr = wid >> 1, wc = wid & 1;
    const int l15 = lane & 15, lg = lane >> 4;
    const int m0 = blockIdx.x * 128;
    const int n0 = blockIdx.y * 128;

    f32x4 acc[4][4] = {};

    for (int k0 = 0; k0 < K; k0 += 64) {
        if (A_BF16) {
            const bf16* A = (const bf16*)Ap;
#pragma unroll
            for (int i = 0; i < 4; ++i) {
                int chunk = t + i * 256;
                int row = chunk >> 3, c8 = (chunk & 7) * 8;
                *(bf16x8*)&As[row][c8] =
                    *(const bf16x8*)(A + (size_t)(m0 + row) * K + k0 + c8);
            }
        } else {
            const float* A = (const float*)Ap;
#pragma unroll
            for (int i = 0; i < 8; ++i) {
                int chunk = t + i * 256;
                int row = chunk >> 4, c4 = (chunk & 15) * 4;
                f32x4 v = *(const f32x4*)(A + (size_t)(m0 + row) * K + k0 + c4);
                bf16x4 o;
#pragma unroll
                for (int j = 0; j < 4; ++j) o[j] = (bf16)v[j];
                *(bf16x4*)&As[row][c4] = o;
            }
        }
#pragma unroll
        for (int i = 0; i < 8; ++i) {
            int chunk = t + i * 256;
            int row = chunk >> 4, c4 = (chunk & 15) * 4;
            f32x4 v = *(const f32x4*)(W + (size_t)(n0 + row) * K + k0 + c4);
            bf16x4 o;
#pragma unroll
            for (int j = 0; j < 4; ++j) o[j] = (bf16)v[j];
            *(bf16x4*)&Bs[row][c4] = o;
        }
        __syncthreads();

#pragma unroll
        for (int kk = 0; kk < 64; kk += 32) {
            bf16x8 af[4], bfv[4];
#pragma unroll
            for (int mi = 0; mi < 4; ++mi)
                af[mi] = *(const bf16x8*)&As[wr * 64 + mi * 16 + l15][kk + lg * 8];
#pragma unroll
            for (int ni = 0; ni < 4; ++ni)
                bfv[ni] = *(const bf16x8*)&Bs[wc * 64 + ni * 16 + l15][kk + lg * 8];
#pragma unroll
            for (int mi = 0; mi < 4; ++mi)
#pragma unroll
                for (int ni = 0; ni < 4; ++ni)
                    acc[mi][ni] = MFMA_BF16(af[mi], bfv[ni], acc[mi][ni]);
        }
        __syncthreads();
    }

#pragma unroll
    for (int ni = 0; ni < 4; ++ni) {
        int col = n0 + wc * 64 + ni * 16 + l15;
        float bv = bias[col];
#pragma unroll
        for (int mi = 0; mi < 4; ++mi) {
#pragma unroll
            for (int r = 0; r < 4; ++r) {
                int row = m0 + wr * 64 + mi * 16 + lg * 4 + r;
                float val = acc[mi][ni][r] + bv;
                if (OUT_F32)
                    ((float*)Cp)[(size_t)row * N + col] = val;
                else
                    ((bf16*)Cp)[(size_t)row * N + col] = (bf16)val;
            }
        }
    }
}

// ---------------------------------------------------------------------------
// Flash attention, static-max softmax, MFMA sum-column, swizzled LDS.
// Grid (S/128, B*H), 256 threads = 4 waves, each wave owns 32 q-rows.
// LDS: Ks 8K (glds, swizzled) + Vt 10K (transposed+ones row, swizzled) +
//      Ps 18K (per-wave, swizzled) = 36.8 KB -> 4 blocks/CU.
// ---------------------------------------------------------------------------
__global__ __launch_bounds__(256, 4) void attn_kernel(
    const bf16* __restrict__ xq, const bf16* __restrict__ xk,
    const bf16* __restrict__ xv, const int* __restrict__ mask,
    bf16* __restrict__ out)
{
    __shared__ __align__(16) bf16 KsF[64 * 64];      // [key][dblk^ (key&7)]
    __shared__ __align__(16) bf16 VtF[80 * 64];      // [d][key-bytes ^ ((d>>3&7)<<4)]; row64=ones
    __shared__ __align__(16) bf16 PsF[4 * 32 * 72];  // per-wave [qrow][key-bytes ^ ((qrow>>1&7)<<4)]

    const int t = threadIdx.x;
    const int lane = t & 63;
    const int wid = t >> 6;
    const int l15 = lane & 15, lg = lane >> 4;
    const int bh = blockIdx.y;
    const int b = bh >> 4, h = bh & 15;
    const int q0 = blockIdx.x * 128;
    constexpr float SC = 0.125f * 1.44269504088896340736f;  // scale * log2(e)
    constexpr float M2 = 12.0f * SC;                        // static softmax shift (raw-score units)

    char* Ksb = (char*)KsF;
    char* Vtb = (char*)VtF;
    char* Psb = (char*)PsF + wid * (32 * 144);

    // ---- Q fragments: direct global -> registers, reused for all K-tiles ----
    bf16x8 aq[2][2];
#pragma unroll
    for (int mi = 0; mi < 2; ++mi)
#pragma unroll
        for (int kh = 0; kh < 2; ++kh)
            aq[mi][kh] = *(const bf16x8*)(xq +
                (size_t)(b * CS + q0 + wid * 32 + mi * 16 + l15) * CDA + h * 64 + kh * 32 + lg * 8);

    // ---- Vt static rows 64..79: row 64 = ones (sum column), 65..79 zeros ----
    {
        bf16 fv = (t < 16) ? (bf16)1.0f : (bf16)0.0f;  // t/16==0 -> row 64
        bf16x4 f4 = {fv, fv, fv, fv};
        *(bf16x4*)(Vtb + 64 * 128 + t * 8) = f4;
    }

    f32x4 accO[2][5] = {};

    for (int kt = 0; kt < CS / 64; ++kt) {
        __syncthreads();  // prior reads of Ks/Vt done (also orders Vt-ones init)

        // ---- K tile: async global->LDS, source pre-swizzled so read XOR lands straight ----
#pragma unroll
        for (int i = 0; i < 2; ++i) {
            int ci = i * 4 + wid;                       // 1 KiB chunk 0..7
            int key = ci * 8 + (lane >> 3);
            int blk = (lane & 7) ^ ((lane >> 3) & 7);   // (key&7) == (lane>>3)&7
            const bf16* src = xk + (size_t)(b * CS + kt * 64 + key) * CDA + h * 64 + blk * 8;
            __builtin_amdgcn_global_load_lds(
                (const __attribute__((address_space(1))) void*)src,
                (__attribute__((address_space(3))) void*)(Ksb + ci * 1024), 16, 0, 0);
        }
        // ---- V tile: reg-staged transpose, swizzled scalar writes ----
#pragma unroll
        for (int i = 0; i < 2; ++i) {
            int chunk = t + i * 256;
            int row = chunk >> 3;            // key
            int c8 = (chunk & 7) * 8;        // d base
            int x = (chunk & 7) << 4;        // == ((d>>3)&7)<<4 for all j
            bf16x8 v = *(const bf16x8*)(xv + (size_t)(b * CS + kt * 64 + row) * CDA + h * 64 + c8);
#pragma unroll
            for (int j = 0; j < 8; ++j)
                *(bf16*)(Vtb + (c8 + j) * 128 + ((row * 2) ^ x)) = v[j];
        }
        __syncthreads();

        // ---- QK^T ----
        f32x4 s[2][4] = {};
#pragma unroll
        for (int kh = 0; kh < 2; ++kh) {
            bf16x8 bk[4];
#pragma unroll
            for (int ni = 0; ni < 4; ++ni) {
                int key = ni * 16 + l15;
                bk[ni] = *(const bf16x8*)(Ksb + key * 128 +
                                          ((kh * 64 + lg * 16) ^ ((key & 7) << 4)));
            }
#pragma unroll
            for (int mi = 0; mi < 2; ++mi)
#pragma unroll
                for (int ni = 0; ni < 4; ++ni)
                    s[mi][ni] = MFMA_BF16(aq[mi][kh], bk[ni], s[mi][ni]);
        }

        // ---- static-max softmax: p = 2^(s*SC - M2); masked -> 0 ----
        int mk[4];
#pragma unroll
        for (int ni = 0; ni < 4; ++ni)
            mk[ni] = mask[b * CS + kt * 64 + ni * 16 + l15];
#pragma unroll
        for (int mi = 0; mi < 2; ++mi)
#pragma unroll
            for (int ni = 0; ni < 4; ++ni)
#pragma unroll
                for (int r = 0; r < 4; ++r) {
                    float s2 = __builtin_fmaf(s[mi][ni][r], SC, -M2);
                    s2 = (mk[ni] == 0) ? -1.0e30f : s2;
                    float p = exp2f(s2);
                    int qrow = mi * 16 + lg * 4 + r;
                    *(bf16*)(Psb + qrow * 144 +
                             (((ni * 16 + l15) * 2) ^ (((qrow >> 1) & 7) << 4))) = (bf16)p;
                }
        __builtin_amdgcn_sched_barrier(0);  // keep ds_writes before PV ds_reads (same-wave RAW)

        // ---- PV (+ ones sum-column di=4) ----
#pragma unroll
        for (int kks = 0; kks < 2; ++kks) {
            bf16x8 ap[2], bv[5];
#pragma unroll
            for (int mi = 0; mi < 2; ++mi) {
                int qrow = mi * 16 + l15;
                ap[mi] = *(const bf16x8*)(Psb + qrow * 144 +
                                          ((kks * 64 + lg * 16) ^ (((qrow >> 1) & 7) << 4)));
            }
#pragma unroll
            for (int di = 0; di < 5; ++di) {
                int d = di * 16 + l15;
                bv[di] = *(const bf16x8*)(Vtb + d * 128 +
                                          ((kks * 64 + lg * 16) ^ (((d >> 3) & 7) << 4)));
            }
#pragma unroll
            for (int mi = 0; mi < 2; ++mi)
#pragma unroll
                for (int di = 0; di < 5; ++di)
                    accO[mi][di] = MFMA_BF16(ap[mi], bv[di], accO[mi][di]);
        }
    }

    // ---- epilogue: divide by sum column (col 64 lives in lane l15==0 of each lg group) ----
#pragma unroll
    for (int mi = 0; mi < 2; ++mi)
#pragma unroll
        for (int r = 0; r < 4; ++r) {
            float lsum = __shfl(accO[mi][4][r], lane & 48);
            float inv = 1.0f / lsum;
#pragma unroll
            for (int di = 0; di < 4; ++di) {
                int row = q0 + wid * 32 + mi * 16 + lg * 4 + r;
                int col = h * 64 + di * 16 + l15;
                out[(size_t)(b * CS + row) * CDA + col] = (bf16)(accO[mi][di][r] * inv);
            }
        }
}

// ---------------------------------------------------------------------------
extern "C" void kernel_launch(void* const* d_in, const int* in_sizes, int n_in,
                              void* d_out, int out_size, void* d_ws, size_t ws_size,
                              hipStream_t stream)
{
    const float* q   = (const float*)d_in[0];
    const float* k   = (const float*)d_in[1];
    const float* v   = (const float*)d_in[2];
    const int*   msk = (const int*)d_in[3];
    const float* w_q = (const float*)d_in[4];
    const float* b_q = (const float*)d_in[5];
    const float* w_k = (const float*)d_in[6];
    const float* b_k = (const float*)d_in[7];
    const float* w_v = (const float*)d_in[8];
    const float* b_v = (const float*)d_in[9];
    const float* w_o = (const float*)d_in[10];
    const float* b_o = (const float*)d_in[11];

    bf16* xq = (bf16*)d_ws;
    bf16* xk = xq + (size_t)CM * CDA;
    bf16* xv = xk + (size_t)CM * CDA;
    bf16* at = xv + (size_t)CM * CDA;

    dim3 gp(CM / 128, CDA / 128);
    gemm_nt_bias<false, false><<<gp, 256, 0, stream>>>((const void*)q, w_q, b_q, (void*)xq, CM, CDA, CD);
    gemm_nt_bias<false, false><<<gp, 256, 0, stream>>>((const void*)k, w_k, b_k, (void*)xk, CM, CDA, CD);
    gemm_nt_bias<false, false><<<gp, 256, 0, stream>>>((const void*)v, w_v, b_v, (void*)xv, CM, CDA, CD);

    attn_kernel<<<dim3(CS / 128, CB * CH), 256, 0, stream>>>(xq, xk, xv, msk, at);

    gemm_nt_bias<true, true><<<dim3(CM / 128, CD / 128), 256, 0, stream>>>(
        (const void*)at, w_o, b_o, d_out, CM, CD, CDA);
}

// Round 4
// 274.308 us; speedup vs baseline: 1.8710x; 1.8710x over previous
//
#include <hip/hip_runtime.h>
#include <hip/hip_bf16.h>
#include <cstdint>
#include <cstddef>

typedef __bf16 bf16;
typedef __attribute__((ext_vector_type(8))) __bf16 bf16x8;
typedef __attribute__((ext_vector_type(4))) __bf16 bf16x4;
typedef __attribute__((ext_vector_type(4))) float f32x4;
typedef __attribute__((ext_vector_type(4))) int i32x4;

#define MFMA_BF16(a, b, c) __builtin_amdgcn_mfma_f32_16x16x32_bf16((a), (b), (c), 0, 0, 0)

constexpr int CB = 4;       // batch
constexpr int CS = 2048;    // seq
constexpr int CD = 1024;    // model dim
constexpr int CDA = 1024;   // attn dim
constexpr int CH = 16;      // heads
constexpr int CM = CB * CS; // 8192 rows

// ---------------------------------------------------------------------------
// GEMM: C[M,N] = A[M,K] * W[N,K]^T + bias[N]  (unchanged)
// ---------------------------------------------------------------------------
template <bool A_BF16, bool OUT_F32>
__global__ __launch_bounds__(256) void gemm_nt_bias(
    const void* __restrict__ Ap, const float* __restrict__ W,
    const float* __restrict__ bias, void* __restrict__ Cp,
    int M, int N, int K)
{
    __shared__ bf16 As[128][72];
    __shared__ bf16 Bs[128][72];

    const int t = threadIdx.x;
    const int lane = t & 63;
    const int wid = t >> 6;
    const int wr = wid >> 1, wc = wid & 1;
    const int l15 = lane & 15, lg = lane >> 4;
    const int m0 = blockIdx.x * 128;
    const int n0 = blockIdx.y * 128;

    f32x4 acc[4][4] = {};

    for (int k0 = 0; k0 < K; k0 += 64) {
        if (A_BF16) {
            const bf16* A = (const bf16*)Ap;
#pragma unroll
            for (int i = 0; i < 4; ++i) {
                int chunk = t + i * 256;
                int row = chunk >> 3, c8 = (chunk & 7) * 8;
                *(bf16x8*)&As[row][c8] =
                    *(const bf16x8*)(A + (size_t)(m0 + row) * K + k0 + c8);
            }
        } else {
            const float* A = (const float*)Ap;
#pragma unroll
            for (int i = 0; i < 8; ++i) {
                int chunk = t + i * 256;
                int row = chunk >> 4, c4 = (chunk & 15) * 4;
                f32x4 v = *(const f32x4*)(A + (size_t)(m0 + row) * K + k0 + c4);
                bf16x4 o;
#pragma unroll
                for (int j = 0; j < 4; ++j) o[j] = (bf16)v[j];
                *(bf16x4*)&As[row][c4] = o;
            }
        }
#pragma unroll
        for (int i = 0; i < 8; ++i) {
            int chunk = t + i * 256;
            int row = chunk >> 4, c4 = (chunk & 15) * 4;
            f32x4 v = *(const f32x4*)(W + (size_t)(n0 + row) * K + k0 + c4);
            bf16x4 o;
#pragma unroll
            for (int j = 0; j < 4; ++j) o[j] = (bf16)v[j];
            *(bf16x4*)&Bs[row][c4] = o;
        }
        __syncthreads();

#pragma unroll
        for (int kk = 0; kk < 64; kk += 32) {
            bf16x8 af[4], bfv[4];
#pragma unroll
            for (int mi = 0; mi < 4; ++mi)
                af[mi] = *(const bf16x8*)&As[wr * 64 + mi * 16 + l15][kk + lg * 8];
#pragma unroll
            for (int ni = 0; ni < 4; ++ni)
                bfv[ni] = *(const bf16x8*)&Bs[wc * 64 + ni * 16 + l15][kk + lg * 8];
#pragma unroll
            for (int mi = 0; mi < 4; ++mi)
#pragma unroll
                for (int ni = 0; ni < 4; ++ni)
                    acc[mi][ni] = MFMA_BF16(af[mi], bfv[ni], acc[mi][ni]);
        }
        __syncthreads();
    }

#pragma unroll
    for (int ni = 0; ni < 4; ++ni) {
        int col = n0 + wc * 64 + ni * 16 + l15;
        float bv = bias[col];
#pragma unroll
        for (int mi = 0; mi < 4; ++mi) {
#pragma unroll
            for (int r = 0; r < 4; ++r) {
                int row = m0 + wr * 64 + mi * 16 + lg * 4 + r;
                float val = acc[mi][ni][r] + bv;
                if (OUT_F32)
                    ((float*)Cp)[(size_t)row * N + col] = val;
                else
                    ((bf16*)Cp)[(size_t)row * N + col] = (bf16)val;
            }
        }
    }
}

// ---------------------------------------------------------------------------
// Flash attention. 512 threads = 8 waves, 256 q-rows/block (32 per wave).
// Grid: 1-D 512 with XCD swizzle so all 8 q-blocks of a (b,h) share an XCD L2.
// Swapped QK^T (mfma(K,Q) -> S^T[key][qrow]) so P-writes are ds_write_b64.
// Static-max softmax (scores bounded), sum via MFMA ones-column (in-register).
// LDS: Ks 8K (glds, src-preswizzled) + Vt 8K (transposed, swizzled) +
//      Ps 8x4.5K = 52 KB -> 2 blocks/CU.
// ---------------------------------------------------------------------------
__global__ __launch_bounds__(512, 4) void attn_kernel(
    const bf16* __restrict__ xq, const bf16* __restrict__ xk,
    const bf16* __restrict__ xv, const int* __restrict__ mask,
    bf16* __restrict__ out)
{
    __shared__ __align__(16) bf16 KsF[64 * 64];      // [key][dblk ^ (key&7)]
    __shared__ __align__(16) bf16 VtF[64 * 64];      // [d][key-bytes ^ ((d>>3&7)<<4)]
    __shared__ __align__(16) bf16 PsF[8 * 32 * 72];  // per-wave [qrow][key-bytes ^ ((qrow>>1&7)<<4)]

    const int t = threadIdx.x;
    const int lane = t & 63;
    const int wid = t >> 6;                    // 0..7
    const int l15 = lane & 15, lg = lane >> 4;
    // XCD-aware decode: all 8 q-tiles of a bh share id%8 (same XCD)
    const int g = blockIdx.x;
    const int j = g >> 3;
    const int bh = (g & 7) * 8 + (j & 7);
    const int qt = j >> 3;                     // 0..7
    const int b = bh >> 4, h = bh & 15;
    const int q0 = qt * 256;
    constexpr float SC = 0.125f * 1.44269504088896340736f;  // scale * log2(e)
    constexpr float M2 = 12.0f * SC;                        // static softmax shift

    char* Ksb = (char*)KsF;
    char* Vtb = (char*)VtF;
    char* Psb = (char*)PsF + wid * (32 * 144);

    // ---- Q fragments: global -> registers once (B-operand of swapped QK^T) ----
    bf16x8 aq[2][2];
#pragma unroll
    for (int mi = 0; mi < 2; ++mi)
#pragma unroll
        for (int kh = 0; kh < 2; ++kh)
            aq[mi][kh] = *(const bf16x8*)(xq +
                (size_t)(b * CS + q0 + wid * 32 + mi * 16 + l15) * CDA + h * 64 + kh * 32 + lg * 8);

    // ---- ones-column B-frag for row sums (V^T row 64 == 1, rows 65.. == 0) ----
    bf16x8 onescol;
    {
        bf16 fv = (l15 == 0) ? (bf16)1.0f : (bf16)0.0f;
#pragma unroll
        for (int jj = 0; jj < 8; ++jj) onescol[jj] = fv;
    }

    f32x4 accO[2][5] = {};

    for (int kt = 0; kt < CS / 64; ++kt) {
        __syncthreads();  // prior tile's reads of Ks/Vt done

        // ---- K tile: async global->LDS; source pre-swizzled so swizzled read lands straight ----
        {
            int key = wid * 8 + (lane >> 3);
            int blk = (lane & 7) ^ ((lane >> 3) & 7);
            const bf16* src = xk + (size_t)(b * CS + kt * 64 + key) * CDA + h * 64 + blk * 8;
            __builtin_amdgcn_global_load_lds(
                (const __attribute__((address_space(1))) void*)src,
                (__attribute__((address_space(3))) void*)(Ksb + wid * 1024), 16, 0, 0);
        }
        // ---- V tile: reg-staged transpose, swizzled scalar writes ----
        {
            int row = t >> 3;                // key 0..63
            int c8 = (t & 7) * 8;            // d base
            int x = (t & 7) << 4;            // ((d>>3)&7)<<4
            bf16x8 v = *(const bf16x8*)(xv + (size_t)(b * CS + kt * 64 + row) * CDA + h * 64 + c8);
#pragma unroll
            for (int jj = 0; jj < 8; ++jj)
                *(bf16*)(Vtb + (c8 + jj) * 128 + ((row * 2) ^ x)) = v[jj];
        }
        __syncthreads();

        // ---- swapped QK^T: sT[ni][mi] tile = S^T[key 16][qrow 16] ----
        f32x4 sT[4][2] = {};
#pragma unroll
        for (int kh = 0; kh < 2; ++kh) {
            bf16x8 bk[4];
#pragma unroll
            for (int ni = 0; ni < 4; ++ni) {
                int key = ni * 16 + l15;
                bk[ni] = *(const bf16x8*)(Ksb + key * 128 +
                                          ((kh * 64 + lg * 16) ^ ((key & 7) << 4)));
            }
#pragma unroll
            for (int ni = 0; ni < 4; ++ni)
#pragma unroll
                for (int mi = 0; mi < 2; ++mi)
                    sT[ni][mi] = MFMA_BF16(bk[ni], aq[mi][kh], sT[ni][mi]);
        }

        // ---- static-max softmax; lane holds 4 consecutive keys per (ni,mi) ----
        const int swz = ((l15 >> 1) & 7) << 4;
#pragma unroll
        for (int ni = 0; ni < 4; ++ni) {
            i32x4 mk = *(const i32x4*)(mask + b * CS + kt * 64 + ni * 16 + lg * 4);
#pragma unroll
            for (int mi = 0; mi < 2; ++mi) {
                bf16x4 p4;
#pragma unroll
                for (int r = 0; r < 4; ++r) {
                    float s2 = __builtin_fmaf(sT[ni][mi][r], SC, -M2);
                    s2 = (mk[r] == 0) ? -1.0e30f : s2;
                    p4[r] = (bf16)exp2f(s2);
                }
                int qrow = mi * 16 + l15;
                *(bf16x4*)(Psb + qrow * 144 + ((ni * 32 + lg * 8) ^ swz)) = p4;
            }
        }
        __builtin_amdgcn_sched_barrier(0);  // keep P ds_writes before PV ds_reads (same-wave RAW)

        // ---- PV (+ in-register ones column di=4) ----
#pragma unroll
        for (int kks = 0; kks < 2; ++kks) {
            bf16x8 ap[2], bv[4];
#pragma unroll
            for (int mi = 0; mi < 2; ++mi) {
                int qrow = mi * 16 + l15;
                ap[mi] = *(const bf16x8*)(Psb + qrow * 144 +
                                          ((kks * 64 + lg * 16) ^ (((qrow >> 1) & 7) << 4)));
            }
#pragma unroll
            for (int di = 0; di < 4; ++di) {
                int d = di * 16 + l15;
                bv[di] = *(const bf16x8*)(Vtb + d * 128 +
                                          ((kks * 64 + lg * 16) ^ (((d >> 3) & 7) << 4)));
            }
#pragma unroll
            for (int mi = 0; mi < 2; ++mi) {
#pragma unroll
                for (int di = 0; di < 4; ++di)
                    accO[mi][di] = MFMA_BF16(ap[mi], bv[di], accO[mi][di]);
                accO[mi][4] = MFMA_BF16(ap[mi], onescol, accO[mi][4]);
            }
        }
    }

    // ---- epilogue: divide by sum, stage in per-wave Ps, coalesced b128 stores ----
#pragma unroll
    for (int mi = 0; mi < 2; ++mi)
#pragma unroll
        for (int r = 0; r < 4; ++r) {
            float lsum = __shfl(accO[mi][4][r], lane & 48);
            float inv = 1.0f / lsum;
            int qrow = mi * 16 + lg * 4 + r;
            int sw = ((qrow >> 1) & 7) << 4;
#pragma unroll
            for (int di = 0; di < 4; ++di)
                *(bf16*)(Psb + qrow * 144 + (((di * 16 + l15) * 2) ^ sw)) =
                    (bf16)(accO[mi][di][r] * inv);
        }
    __builtin_amdgcn_sched_barrier(0);
#pragma unroll
    for (int i = 0; i < 4; ++i) {
        int qrow = i * 8 + (lane >> 3);
        int chunk = lane & 7;
        bf16x8 o = *(const bf16x8*)(Psb + qrow * 144 +
                                    ((chunk << 4) ^ (((qrow >> 1) & 7) << 4)));
        *(bf16x8*)(out + (size_t)(b * CS + q0 + wid * 32 + qrow) * CDA + h * 64 + chunk * 8) = o;
    }
}

// ---------------------------------------------------------------------------
extern "C" void kernel_launch(void* const* d_in, const int* in_sizes, int n_in,
                              void* d_out, int out_size, void* d_ws, size_t ws_size,
                              hipStream_t stream)
{
    const float* q   = (const float*)d_in[0];
    const float* k   = (const float*)d_in[1];
    const float* v   = (const float*)d_in[2];
    const int*   msk = (const int*)d_in[3];
    const float* w_q = (const float*)d_in[4];
    const float* b_q = (const float*)d_in[5];
    const float* w_k = (const float*)d_in[6];
    const float* b_k = (const float*)d_in[7];
    const float* w_v = (const float*)d_in[8];
    const float* b_v = (const float*)d_in[9];
    const float* w_o = (const float*)d_in[10];
    const float* b_o = (const float*)d_in[11];

    bf16* xq = (bf16*)d_ws;
    bf16* xk = xq + (size_t)CM * CDA;
    bf16* xv = xk + (size_t)CM * CDA;
    bf16* at = xv + (size_t)CM * CDA;

    dim3 gp(CM / 128, CDA / 128);
    gemm_nt_bias<false, false><<<gp, 256, 0, stream>>>((const void*)q, w_q, b_q, (void*)xq, CM, CDA, CD);
    gemm_nt_bias<false, false><<<gp, 256, 0, stream>>>((const void*)k, w_k, b_k, (void*)xk, CM, CDA, CD);
    gemm_nt_bias<false, false><<<gp, 256, 0, stream>>>((const void*)v, w_v, b_v, (void*)xv, CM, CDA, CD);

    attn_kernel<<<dim3(512), 512, 0, stream>>>(xq, xk, xv, msk, at);

    gemm_nt_bias<true, true><<<dim3(CM / 128, CD / 128), 256, 0, stream>>>(
        (const void*)at, w_o, b_o, d_out, CM, CD, CDA);
}

// Round 5
// 267.087 us; speedup vs baseline: 1.9216x; 1.0270x over previous
//
#include <hip/hip_runtime.h>
#include <hip/hip_bf16.h>
#include <cstdint>
#include <cstddef>

typedef __bf16 bf16;
typedef __attribute__((ext_vector_type(8))) __bf16 bf16x8;
typedef __attribute__((ext_vector_type(4))) __bf16 bf16x4;
typedef __attribute__((ext_vector_type(4))) float f32x4;
typedef __attribute__((ext_vector_type(4))) int i32x4;

#define MFMA_BF16(a, b, c) __builtin_amdgcn_mfma_f32_16x16x32_bf16((a), (b), (c), 0, 0, 0)

constexpr int CB = 4;       // batch
constexpr int CS = 2048;    // seq
constexpr int CD = 1024;    // model dim
constexpr int CDA = 1024;   // attn dim
constexpr int CH = 16;      // heads
constexpr int CM = CB * CS; // 8192 rows

// ---------------------------------------------------------------------------
// GEMM: C[M,N] = A[M,K] * W[N,K]^T + bias[N]  (unchanged)
// ---------------------------------------------------------------------------
template <bool A_BF16, bool OUT_F32>
__global__ __launch_bounds__(256) void gemm_nt_bias(
    const void* __restrict__ Ap, const float* __restrict__ W,
    const float* __restrict__ bias, void* __restrict__ Cp,
    int M, int N, int K)
{
    __shared__ bf16 As[128][72];
    __shared__ bf16 Bs[128][72];

    const int t = threadIdx.x;
    const int lane = t & 63;
    const int wid = t >> 6;
    const int wr = wid >> 1, wc = wid & 1;
    const int l15 = lane & 15, lg = lane >> 4;
    const int m0 = blockIdx.x * 128;
    const int n0 = blockIdx.y * 128;

    f32x4 acc[4][4] = {};

    for (int k0 = 0; k0 < K; k0 += 64) {
        if (A_BF16) {
            const bf16* A = (const bf16*)Ap;
#pragma unroll
            for (int i = 0; i < 4; ++i) {
                int chunk = t + i * 256;
                int row = chunk >> 3, c8 = (chunk & 7) * 8;
                *(bf16x8*)&As[row][c8] =
                    *(const bf16x8*)(A + (size_t)(m0 + row) * K + k0 + c8);
            }
        } else {
            const float* A = (const float*)Ap;
#pragma unroll
            for (int i = 0; i < 8; ++i) {
                int chunk = t + i * 256;
                int row = chunk >> 4, c4 = (chunk & 15) * 4;
                f32x4 v = *(const f32x4*)(A + (size_t)(m0 + row) * K + k0 + c4);
                bf16x4 o;
#pragma unroll
                for (int j = 0; j < 4; ++j) o[j] = (bf16)v[j];
                *(bf16x4*)&As[row][c4] = o;
            }
        }
#pragma unroll
        for (int i = 0; i < 8; ++i) {
            int chunk = t + i * 256;
            int row = chunk >> 4, c4 = (chunk & 15) * 4;
            f32x4 v = *(const f32x4*)(W + (size_t)(n0 + row) * K + k0 + c4);
            bf16x4 o;
#pragma unroll
            for (int j = 0; j < 4; ++j) o[j] = (bf16)v[j];
            *(bf16x4*)&Bs[row][c4] = o;
        }
        __syncthreads();

#pragma unroll
        for (int kk = 0; kk < 64; kk += 32) {
            bf16x8 af[4], bfv[4];
#pragma unroll
            for (int mi = 0; mi < 4; ++mi)
                af[mi] = *(const bf16x8*)&As[wr * 64 + mi * 16 + l15][kk + lg * 8];
#pragma unroll
            for (int ni = 0; ni < 4; ++ni)
                bfv[ni] = *(const bf16x8*)&Bs[wc * 64 + ni * 16 + l15][kk + lg * 8];
#pragma unroll
            for (int mi = 0; mi < 4; ++mi)
#pragma unroll
                for (int ni = 0; ni < 4; ++ni)
                    acc[mi][ni] = MFMA_BF16(af[mi], bfv[ni], acc[mi][ni]);
        }
        __syncthreads();
    }

#pragma unroll
    for (int ni = 0; ni < 4; ++ni) {
        int col = n0 + wc * 64 + ni * 16 + l15;
        float bv = bias[col];
#pragma unroll
        for (int mi = 0; mi < 4; ++mi) {
#pragma unroll
            for (int r = 0; r < 4; ++r) {
                int row = m0 + wr * 64 + mi * 16 + lg * 4 + r;
                float val = acc[mi][ni][r] + bv;
                if (OUT_F32)
                    ((float*)Cp)[(size_t)row * N + col] = val;
                else
                    ((bf16*)Cp)[(size_t)row * N + col] = (bf16)val;
            }
        }
    }
}

// ---------------------------------------------------------------------------
// Flash attention. 512 threads = 8 waves, 256 q-rows/block, XCD-swizzled grid.
// Swapped QK^T (S^T in regs, lane l15 = qrow) feeds PV A-operand DIRECTLY:
// lane (l15,lg) holds P for keys {ni*16+lg*4+r} == its A-frag slots
// {kks*32+lg*8+jj} under the column permutation c(s) applied to V's LDS
// layout (PV contraction is order-invariant). P never touches LDS.
// Static-max softmax; row-sum via in-register ones-column MFMA.
// LDS: Ks 8K (glds, src-preswizzled) + Vt 8K (transpose+perm) = 16 KB.
// ---------------------------------------------------------------------------
__global__ __launch_bounds__(512, 4) void attn_kernel(
    const bf16* __restrict__ xq, const bf16* __restrict__ xk,
    const bf16* __restrict__ xv, const int* __restrict__ mask,
    bf16* __restrict__ out)
{
    __shared__ __align__(16) char smem[16384];
    char* Ksb = smem;          // [key][slot*16], slot = dblk ^ (key&7)
    char* Vtb = smem + 8192;   // [d][cperm*2 ^ ((d>>3&7)<<4)]

    const int t = threadIdx.x;
    const int lane = t & 63;
    const int wid = t >> 6;                    // 0..7
    const int l15 = lane & 15, lg = lane >> 4;
    // XCD-aware decode: all 8 q-tiles of a bh share id%8 (same XCD)
    const int g = blockIdx.x;
    const int j = g >> 3;
    const int bh = (g & 7) * 8 + (j & 7);
    const int qt = j >> 3;
    const int b = bh >> 4, h = bh & 15;
    const int q0 = qt * 256;
    constexpr float SC = 0.125f * 1.44269504088896340736f;  // scale * log2(e)
    constexpr float M2 = 12.0f * SC;                        // static softmax shift

    // ---- Q fragments: global -> registers once (B-operand of swapped QK^T) ----
    bf16x8 aq[2][2];
#pragma unroll
    for (int mi = 0; mi < 2; ++mi)
#pragma unroll
        for (int kh = 0; kh < 2; ++kh)
            aq[mi][kh] = *(const bf16x8*)(xq +
                (size_t)(b * CS + q0 + wid * 32 + mi * 16 + l15) * CDA + h * 64 + kh * 32 + lg * 8);

    // ---- ones-column B-frag for row sums ----
    bf16x8 onescol;
    {
        bf16 fv = (l15 == 0) ? (bf16)1.0f : (bf16)0.0f;
#pragma unroll
        for (int jj = 0; jj < 8; ++jj) onescol[jj] = fv;
    }

    f32x4 accO[2][5] = {};

    for (int kt = 0; kt < CS / 64; ++kt) {
        __syncthreads();  // prior tile's reads of Ks/Vt done

        // ---- K tile: async global->LDS; source pre-swizzled ----
        {
            int key = wid * 8 + (lane >> 3);
            int blk = (lane & 7) ^ ((lane >> 3) & 7);
            const bf16* src = xk + (size_t)(b * CS + kt * 64 + key) * CDA + h * 64 + blk * 8;
            __builtin_amdgcn_global_load_lds(
                (const __attribute__((address_space(1))) void*)src,
                (__attribute__((address_space(3))) void*)(Ksb + wid * 1024), 16, 0, 0);
        }
        // ---- V tile: reg-staged transpose into PERMUTED columns ----
        {
            int s = t >> 3;                  // V key-row 0..63
            int c8 = (t & 7) * 8;            // d base
            int x = (t & 7) << 4;            // ((d>>3)&7)<<4
            // column permutation: c5=s5, c4=s3, c3=s2, c2=s4, c1c0=s1s0
            int cp = (s & 32) | ((s & 12) << 1) | ((s & 16) >> 2) | (s & 3);
            bf16x8 v = *(const bf16x8*)(xv + (size_t)(b * CS + kt * 64 + s) * CDA + h * 64 + c8);
#pragma unroll
            for (int jj = 0; jj < 8; ++jj)
                *(bf16*)(Vtb + (c8 + jj) * 128 + ((cp * 2) ^ x)) = v[jj];
        }
        // mask for this tile (keys ni*16 + lg*4 + r)
        i32x4 mk[4];
#pragma unroll
        for (int ni = 0; ni < 4; ++ni)
            mk[ni] = *(const i32x4*)(mask + b * CS + kt * 64 + ni * 16 + lg * 4);
        __syncthreads();

        // ---- swapped QK^T: sT[ni][mi] = S^T[key 16][qrow 16] ----
        f32x4 sT[4][2] = {};
#pragma unroll
        for (int kh = 0; kh < 2; ++kh) {
            bf16x8 bk[4];
#pragma unroll
            for (int ni = 0; ni < 4; ++ni) {
                int key = ni * 16 + l15;
                bk[ni] = *(const bf16x8*)(Ksb + key * 128 +
                                          ((kh * 64 + lg * 16) ^ ((key & 7) << 4)));
            }
#pragma unroll
            for (int ni = 0; ni < 4; ++ni)
#pragma unroll
                for (int mi = 0; mi < 2; ++mi)
                    sT[ni][mi] = MFMA_BF16(bk[ni], aq[mi][kh], sT[ni][mi]);
        }

        // ---- static-max softmax in place: p = 2^(s*SC - M2); masked -> 0 ----
#pragma unroll
        for (int ni = 0; ni < 4; ++ni)
#pragma unroll
            for (int mi = 0; mi < 2; ++mi)
#pragma unroll
                for (int r = 0; r < 4; ++r) {
                    float s2 = __builtin_fmaf(sT[ni][mi][r], SC, -M2);
                    s2 = (mk[ni][r] == 0) ? -1.0e30f : s2;
                    sT[ni][mi][r] = exp2f(s2);
                }

        // ---- pack P into PV A-frags in-register (slot order matches Vt perm) ----
        bf16x8 ap[2][2];
#pragma unroll
        for (int kks = 0; kks < 2; ++kks)
#pragma unroll
            for (int mi = 0; mi < 2; ++mi)
#pragma unroll
                for (int r = 0; r < 4; ++r) {
                    ap[kks][mi][r]     = (bf16)sT[2 * kks][mi][r];
                    ap[kks][mi][4 + r] = (bf16)sT[2 * kks + 1][mi][r];
                }

        // ---- PV (+ in-register ones column di=4) ----
#pragma unroll
        for (int kks = 0; kks < 2; ++kks) {
            bf16x8 bv[4];
#pragma unroll
            for (int di = 0; di < 4; ++di) {
                int d = di * 16 + l15;
                bv[di] = *(const bf16x8*)(Vtb + d * 128 +
                                          ((kks * 64 + lg * 16) ^ (((d >> 3) & 7) << 4)));
            }
#pragma unroll
            for (int mi = 0; mi < 2; ++mi) {
#pragma unroll
                for (int di = 0; di < 4; ++di)
                    accO[mi][di] = MFMA_BF16(ap[kks][mi], bv[di], accO[mi][di]);
                accO[mi][4] = MFMA_BF16(ap[kks][mi], onescol, accO[mi][4]);
            }
        }
    }

    // ---- epilogue: divide by sum, two per-wave staging passes reusing smem ----
    __syncthreads();  // all waves done reading Ks/Vt
    char* Ob = smem + wid * 2048;  // per-wave 16 rows x 128B
#pragma unroll
    for (int mi = 0; mi < 2; ++mi) {
#pragma unroll
        for (int r = 0; r < 4; ++r) {
            float lsum = __shfl(accO[mi][4][r], lane & 48);
            float inv = 1.0f / lsum;
            int qr = lg * 4 + r;
#pragma unroll
            for (int di = 0; di < 4; ++di)
                *(bf16*)(Ob + qr * 128 + (((di * 16 + l15) * 2) ^ ((qr & 7) << 4))) =
                    (bf16)(accO[mi][di][r] * inv);
        }
        __builtin_amdgcn_sched_barrier(0);  // keep stage-writes before readback
#pragma unroll
        for (int i = 0; i < 2; ++i) {
            int rr = i * 8 + (lane >> 3);
            int ch = lane & 7;
            bf16x8 o = *(const bf16x8*)(Ob + rr * 128 + ((ch * 16) ^ ((rr & 7) << 4)));
            *(bf16x8*)(out + (size_t)(b * CS + q0 + wid * 32 + mi * 16 + rr) * CDA +
                       h * 64 + ch * 8) = o;
        }
        __builtin_amdgcn_sched_barrier(0);  // keep mi=1 writes after mi=0 reads (same-wave WAR)
    }
}

// ---------------------------------------------------------------------------
extern "C" void kernel_launch(void* const* d_in, const int* in_sizes, int n_in,
                              void* d_out, int out_size, void* d_ws, size_t ws_size,
                              hipStream_t stream)
{
    const float* q   = (const float*)d_in[0];
    const float* k   = (const float*)d_in[1];
    const float* v   = (const float*)d_in[2];
    const int*   msk = (const int*)d_in[3];
    const float* w_q = (const float*)d_in[4];
    const float* b_q = (const float*)d_in[5];
    const float* w_k = (const float*)d_in[6];
    const float* b_k = (const float*)d_in[7];
    const float* w_v = (const float*)d_in[8];
    const float* b_v = (const float*)d_in[9];
    const float* w_o = (const float*)d_in[10];
    const float* b_o = (const float*)d_in[11];

    bf16* xq = (bf16*)d_ws;
    bf16* xk = xq + (size_t)CM * CDA;
    bf16* xv = xk + (size_t)CM * CDA;
    bf16* at = xv + (size_t)CM * CDA;

    dim3 gp(CM / 128, CDA / 128);
    gemm_nt_bias<false, false><<<gp, 256, 0, stream>>>((const void*)q, w_q, b_q, (void*)xq, CM, CDA, CD);
    gemm_nt_bias<false, false><<<gp, 256, 0, stream>>>((const void*)k, w_k, b_k, (void*)xk, CM, CDA, CD);
    gemm_nt_bias<false, false><<<gp, 256, 0, stream>>>((const void*)v, w_v, b_v, (void*)xv, CM, CDA, CD);

    attn_kernel<<<dim3(512), 512, 0, stream>>>(xq, xk, xv, msk, at);

    gemm_nt_bias<true, true><<<dim3(CM / 128, CD / 128), 256, 0, stream>>>(
        (const void*)at, w_o, b_o, d_out, CM, CD, CDA);
}

// Round 6
// 239.236 us; speedup vs baseline: 2.1453x; 1.1164x over previous
//
#include <hip/hip_runtime.h>
#include <hip/hip_bf16.h>
#include <cstdint>
#include <cstddef>

typedef __bf16 bf16;
typedef __attribute__((ext_vector_type(8))) __bf16 bf16x8;
typedef __attribute__((ext_vector_type(4))) __bf16 bf16x4;
typedef __attribute__((ext_vector_type(4))) float f32x4;
typedef __attribute__((ext_vector_type(4))) int i32x4;

#define MFMA_BF16(a, b, c) __builtin_amdgcn_mfma_f32_16x16x32_bf16((a), (b), (c), 0, 0, 0)

constexpr int CB = 4;       // batch
constexpr int CS = 2048;    // seq
constexpr int CD = 1024;    // model dim
constexpr int CDA = 1024;   // attn dim
constexpr int CH = 16;      // heads
constexpr int CM = CB * CS; // 8192 rows
constexpr int NT = CS / 64; // 32 key tiles

// ---------------------------------------------------------------------------
// GEMM: C = A[M,K] * W[N,K]^T + bias[N]
// OMODE 0: C[M,N] bf16.  1: C[M,N] f32.  2: C^T[N,CM] bf16 with the
// within-64 column permutation cp() on the M index (V^T for attention;
// column slot c holds seq-position key(c) matching the PV A-frag order).
// ---------------------------------------------------------------------------
template <bool A_BF16, int OMODE>
__global__ __launch_bounds__(256) void gemm_nt_bias(
    const void* __restrict__ Ap, const float* __restrict__ W,
    const float* __restrict__ bias, void* __restrict__ Cp,
    int M, int N, int K)
{
    __shared__ bf16 As[128][72];
    __shared__ bf16 Bs[128][72];

    const int t = threadIdx.x;
    const int lane = t & 63;
    const int wid = t >> 6;
    const int wr = wid >> 1, wc = wid & 1;
    const int l15 = lane & 15, lg = lane >> 4;
    const int m0 = blockIdx.x * 128;
    const int n0 = blockIdx.y * 128;

    f32x4 acc[4][4] = {};

    for (int k0 = 0; k0 < K; k0 += 64) {
        if (A_BF16) {
            const bf16* A = (const bf16*)Ap;
#pragma unroll
            for (int i = 0; i < 4; ++i) {
                int chunk = t + i * 256;
                int row = chunk >> 3, c8 = (chunk & 7) * 8;
                *(bf16x8*)&As[row][c8] =
                    *(const bf16x8*)(A + (size_t)(m0 + row) * K + k0 + c8);
            }
        } else {
            const float* A = (const float*)Ap;
#pragma unroll
            for (int i = 0; i < 8; ++i) {
                int chunk = t + i * 256;
                int row = chunk >> 4, c4 = (chunk & 15) * 4;
                f32x4 v = *(const f32x4*)(A + (size_t)(m0 + row) * K + k0 + c4);
                bf16x4 o;
#pragma unroll
                for (int jj = 0; jj < 4; ++jj) o[jj] = (bf16)v[jj];
                *(bf16x4*)&As[row][c4] = o;
            }
        }
#pragma unroll
        for (int i = 0; i < 8; ++i) {
            int chunk = t + i * 256;
            int row = chunk >> 4, c4 = (chunk & 15) * 4;
            f32x4 v = *(const f32x4*)(W + (size_t)(n0 + row) * K + k0 + c4);
            bf16x4 o;
#pragma unroll
            for (int jj = 0; jj < 4; ++jj) o[jj] = (bf16)v[jj];
            *(bf16x4*)&Bs[row][c4] = o;
        }
        __syncthreads();

#pragma unroll
        for (int kk = 0; kk < 64; kk += 32) {
            bf16x8 af[4], bfv[4];
#pragma unroll
            for (int mi = 0; mi < 4; ++mi)
                af[mi] = *(const bf16x8*)&As[wr * 64 + mi * 16 + l15][kk + lg * 8];
#pragma unroll
            for (int ni = 0; ni < 4; ++ni)
                bfv[ni] = *(const bf16x8*)&Bs[wc * 64 + ni * 16 + l15][kk + lg * 8];
#pragma unroll
            for (int mi = 0; mi < 4; ++mi)
#pragma unroll
                for (int ni = 0; ni < 4; ++ni)
                    acc[mi][ni] = MFMA_BF16(af[mi], bfv[ni], acc[mi][ni]);
        }
        __syncthreads();
    }

    if (OMODE == 2) {
        // C^T with permuted columns: value for (m, n) -> xvT[n][ (m&~63) | cp(m&63) ]
        bf16* C = (bf16*)Cp;
        const int mblock = m0 + wr * 64;
#pragma unroll
        for (int ni = 0; ni < 4; ++ni) {
            int n = n0 + wc * 64 + ni * 16 + l15;
            float bv = bias[n];
#pragma unroll
            for (int mi = 0; mi < 4; ++mi) {
                int s = mi * 16 + lg * 4;  // s&3 == 0
                int cps = (s & 32) | ((s & 12) << 1) | ((s & 16) >> 2);
                bf16x4 o;
#pragma unroll
                for (int r = 0; r < 4; ++r) o[r] = (bf16)(acc[mi][ni][r] + bv);
                *(bf16x4*)(C + (size_t)n * CM + mblock + cps) = o;
            }
        }
    } else {
#pragma unroll
        for (int ni = 0; ni < 4; ++ni) {
            int col = n0 + wc * 64 + ni * 16 + l15;
            float bv = bias[col];
#pragma unroll
            for (int mi = 0; mi < 4; ++mi) {
#pragma unroll
                for (int r = 0; r < 4; ++r) {
                    int row = m0 + wr * 64 + mi * 16 + lg * 4 + r;
                    float val = acc[mi][ni][r] + bv;
                    if (OMODE == 1)
                        ((float*)Cp)[(size_t)row * N + col] = val;
                    else
                        ((bf16*)Cp)[(size_t)row * N + col] = (bf16)val;
                }
            }
        }
    }
}

// ---------------------------------------------------------------------------
// Flash attention. 512 threads = 8 waves, 256 q-rows/block, XCD-swizzled grid.
// K and V^T both staged via global_load_lds (src pre-swizzled, LDS linear),
// DOUBLE-BUFFERED: next tile's glds issued before this tile's compute; the
// one __syncthreads per iter drains them after a full compute phase.
// Swapped QK^T keeps S^T in regs; P feeds PV A-operand directly (key order
// matched by xvT's cp() column permutation). Static-max softmax; row sums
// via in-register ones-column MFMA. LDS: 2 x (Ks 8K + Vt 8K) = 32 KB.
// ---------------------------------------------------------------------------
__global__ __launch_bounds__(512, 4) void attn_kernel(
    const bf16* __restrict__ xq, const bf16* __restrict__ xk,
    const bf16* __restrict__ xvT, const int* __restrict__ mask,
    bf16* __restrict__ out)
{
    __shared__ __align__(16) char smem[32768];

    const int t = threadIdx.x;
    const int lane = t & 63;
    const int wid = t >> 6;                    // 0..7
    const int l15 = lane & 15, lg = lane >> 4;
    // XCD-aware decode: all 8 q-tiles of a bh share id%8 (same XCD)
    const int g = blockIdx.x;
    const int j = g >> 3;
    const int bh = (g & 7) * 8 + (j & 7);
    const int qt = j >> 3;
    const int b = bh >> 4, h = bh & 15;
    const int q0 = qt * 256;
    constexpr float SC = 0.125f * 1.44269504088896340736f;  // scale * log2(e)
    constexpr float M2 = 12.0f * SC;                        // static softmax shift

    // per-lane staging sources (16B each; LDS dest is wave-uniform + lane*16)
    const int sub = lane >> 3;                 // which of 8 rows this lane fills
    const int sb  = (lane & 7) ^ sub;          // bank-swizzled 16B column block
    const bf16* kbase = xk + (size_t)(b * CS + wid * 8 + sub) * CDA + h * 64 + sb * 8;
    const bf16* vbase = xvT + (size_t)(h * 64 + wid * 8 + sub) * CM + b * CS + sb * 8;

#define STAGE(bufi, ktt)                                                           \
    {                                                                              \
        char* Kd = smem + (bufi) * 16384 + wid * 1024;                             \
        char* Vd = smem + (bufi) * 16384 + 8192 + wid * 1024;                      \
        __builtin_amdgcn_global_load_lds(                                          \
            (const __attribute__((address_space(1))) void*)(kbase + (size_t)(ktt) * 64 * CDA), \
            (__attribute__((address_space(3))) void*)Kd, 16, 0, 0);                \
        __builtin_amdgcn_global_load_lds(                                          \
            (const __attribute__((address_space(1))) void*)(vbase + (ktt) * 64),   \
            (__attribute__((address_space(3))) void*)Vd, 16, 0, 0);                \
    }

    // ---- Q fragments: global -> registers once (B-operand of swapped QK^T) ----
    bf16x8 aq[2][2];
#pragma unroll
    for (int mi = 0; mi < 2; ++mi)
#pragma unroll
        for (int kh = 0; kh < 2; ++kh)
            aq[mi][kh] = *(const bf16x8*)(xq +
                (size_t)(b * CS + q0 + wid * 32 + mi * 16 + l15) * CDA + h * 64 + kh * 32 + lg * 8);

    // ---- ones-column B-frag for row sums ----
    bf16x8 onescol;
    {
        bf16 fv = (l15 == 0) ? (bf16)1.0f : (bf16)0.0f;
#pragma unroll
        for (int jj = 0; jj < 8; ++jj) onescol[jj] = fv;
    }

    f32x4 accO[2][5] = {};

    STAGE(0, 0);
    __syncthreads();

    for (int kt = 0; kt < NT; ++kt) {
        const int cur = kt & 1;
        char* Ksb = smem + cur * 16384;
        char* Vtb = Ksb + 8192;

        // mask first, so its mid-phase waitcnt leaves the prefetch glds in flight
        i32x4 mk[4];
#pragma unroll
        for (int ni = 0; ni < 4; ++ni)
            mk[ni] = *(const i32x4*)(mask + b * CS + kt * 64 + ni * 16 + lg * 4);

        if (kt + 1 < NT) STAGE(cur ^ 1, kt + 1);

        // ---- swapped QK^T: sT[ni][mi] = S^T[key 16][qrow 16] ----
        f32x4 sT[4][2] = {};
#pragma unroll
        for (int kh = 0; kh < 2; ++kh) {
            bf16x8 bk[4];
#pragma unroll
            for (int ni = 0; ni < 4; ++ni) {
                int key = ni * 16 + l15;
                bk[ni] = *(const bf16x8*)(Ksb + key * 128 +
                                          ((kh * 64 + lg * 16) ^ ((key & 7) << 4)));
            }
#pragma unroll
            for (int ni = 0; ni < 4; ++ni)
#pragma unroll
                for (int mi = 0; mi < 2; ++mi)
                    sT[ni][mi] = MFMA_BF16(bk[ni], aq[mi][kh], sT[ni][mi]);
        }

        // ---- static-max softmax in place: p = 2^(s*SC - M2); masked -> 0 ----
#pragma unroll
        for (int ni = 0; ni < 4; ++ni)
#pragma unroll
            for (int mi = 0; mi < 2; ++mi)
#pragma unroll
                for (int r = 0; r < 4; ++r) {
                    float s2 = __builtin_fmaf(sT[ni][mi][r], SC, -M2);
                    s2 = (mk[ni][r] == 0) ? -1.0e30f : s2;
                    sT[ni][mi][r] = exp2f(s2);
                }

        // ---- pack P into PV A-frags (in-register; order matches xvT perm) ----
        bf16x8 ap[2][2];
#pragma unroll
        for (int kks = 0; kks < 2; ++kks)
#pragma unroll
            for (int mi = 0; mi < 2; ++mi)
#pragma unroll
                for (int r = 0; r < 4; ++r) {
                    ap[kks][mi][r]     = (bf16)sT[2 * kks][mi][r];
                    ap[kks][mi][4 + r] = (bf16)sT[2 * kks + 1][mi][r];
                }

        // ---- PV (+ in-register ones column di=4) ----
#pragma unroll
        for (int kks = 0; kks < 2; ++kks) {
            bf16x8 bv[4];
#pragma unroll
            for (int di = 0; di < 4; ++di) {
                int d = di * 16 + l15;
                bv[di] = *(const bf16x8*)(Vtb + d * 128 +
                                          ((kks * 64 + lg * 16) ^ ((d & 7) << 4)));
            }
#pragma unroll
            for (int mi = 0; mi < 2; ++mi) {
#pragma unroll
                for (int di = 0; di < 4; ++di)
                    accO[mi][di] = MFMA_BF16(ap[kks][mi], bv[di], accO[mi][di]);
                accO[mi][4] = MFMA_BF16(ap[kks][mi], onescol, accO[mi][4]);
            }
        }

        __syncthreads();  // drains this iter's glds; orders cur-buffer reuse
    }
#undef STAGE

    // ---- epilogue: divide by sum, per-wave staging in smem, b128 stores ----
    char* Ob = smem + wid * 2048;  // 16 rows x 128B per wave (buf0 region)
#pragma unroll
    for (int mi = 0; mi < 2; ++mi) {
#pragma unroll
        for (int r = 0; r < 4; ++r) {
            float lsum = __shfl(accO[mi][4][r], lane & 48);
            float inv = 1.0f / lsum;
            int qr = lg * 4 + r;
#pragma unroll
            for (int di = 0; di < 4; ++di)
                *(bf16*)(Ob + qr * 128 + (((di * 16 + l15) * 2) ^ ((qr & 7) << 4))) =
                    (bf16)(accO[mi][di][r] * inv);
        }
        __builtin_amdgcn_sched_barrier(0);  // keep stage-writes before readback
#pragma unroll
        for (int i = 0; i < 2; ++i) {
            int rr = i * 8 + (lane >> 3);
            int ch = lane & 7;
            bf16x8 o = *(const bf16x8*)(Ob + rr * 128 + ((ch * 16) ^ ((rr & 7) << 4)));
            *(bf16x8*)(out + (size_t)(b * CS + q0 + wid * 32 + mi * 16 + rr) * CDA +
                       h * 64 + ch * 8) = o;
        }
        __builtin_amdgcn_sched_barrier(0);  // keep mi=1 writes after mi=0 reads
    }
}

// ---------------------------------------------------------------------------
extern "C" void kernel_launch(void* const* d_in, const int* in_sizes, int n_in,
                              void* d_out, int out_size, void* d_ws, size_t ws_size,
                              hipStream_t stream)
{
    const float* q   = (const float*)d_in[0];
    const float* k   = (const float*)d_in[1];
    const float* v   = (const float*)d_in[2];
    const int*   msk = (const int*)d_in[3];
    const float* w_q = (const float*)d_in[4];
    const float* b_q = (const float*)d_in[5];
    const float* w_k = (const float*)d_in[6];
    const float* b_k = (const float*)d_in[7];
    const float* w_v = (const float*)d_in[8];
    const float* b_v = (const float*)d_in[9];
    const float* w_o = (const float*)d_in[10];
    const float* b_o = (const float*)d_in[11];

    bf16* xq  = (bf16*)d_ws;
    bf16* xk  = xq + (size_t)CM * CDA;
    bf16* xvT = xk + (size_t)CM * CDA;   // [DA][CM], keys permuted within 64-blocks
    bf16* at  = xvT + (size_t)CM * CDA;

    dim3 gp(CM / 128, CDA / 128);
    gemm_nt_bias<false, 0><<<gp, 256, 0, stream>>>((const void*)q, w_q, b_q, (void*)xq, CM, CDA, CD);
    gemm_nt_bias<false, 0><<<gp, 256, 0, stream>>>((const void*)k, w_k, b_k, (void*)xk, CM, CDA, CD);
    gemm_nt_bias<false, 2><<<gp, 256, 0, stream>>>((const void*)v, w_v, b_v, (void*)xvT, CM, CDA, CD);

    attn_kernel<<<dim3(512), 512, 0, stream>>>(xq, xk, xvT, msk, at);

    gemm_nt_bias<true, 1><<<dim3(CM / 128, CD / 128), 256, 0, stream>>>(
        (const void*)at, w_o, b_o, d_out, CM, CD, CDA);
}

// Round 7
// 223.823 us; speedup vs baseline: 2.2931x; 1.0689x over previous
//
#include <hip/hip_runtime.h>
#include <hip/hip_bf16.h>
#include <cstdint>
#include <cstddef>

typedef __bf16 bf16;
typedef __attribute__((ext_vector_type(8))) __bf16 bf16x8;
typedef __attribute__((ext_vector_type(4))) __bf16 bf16x4;
typedef __attribute__((ext_vector_type(4))) float f32x4;
typedef __attribute__((ext_vector_type(4))) int i32x4;

#define MFMA_BF16(a, b, c) __builtin_amdgcn_mfma_f32_16x16x32_bf16((a), (b), (c), 0, 0, 0)

constexpr int CB = 4;       // batch
constexpr int CS = 2048;    // seq
constexpr int CD = 1024;    // model dim
constexpr int CDA = 1024;   // attn dim
constexpr int CH = 16;      // heads
constexpr int CM = CB * CS; // 8192 rows
constexpr int NT = CS / 64; // 32 key tiles

// ---------------------------------------------------------------------------
// Weight pre-convert: 4 x [1024x1024] fp32 -> bf16 (linear layout).
// ---------------------------------------------------------------------------
__global__ __launch_bounds__(256) void cvt_w4(
    const float* __restrict__ s0, const float* __restrict__ s1,
    const float* __restrict__ s2, const float* __restrict__ s3,
    bf16* __restrict__ dst)
{
    int bid = blockIdx.x;
    int m = bid >> 9;                                 // 512 blocks per matrix
    size_t li = ((size_t)(bid & 511) * 256 + threadIdx.x) * 8;
    const float* s = (m == 0) ? s0 : (m == 1) ? s1 : (m == 2) ? s2 : s3;
    f32x4 a = *(const f32x4*)(s + li);
    f32x4 c = *(const f32x4*)(s + li + 4);
    bf16x8 o;
#pragma unroll
    for (int j = 0; j < 4; ++j) { o[j] = (bf16)a[j]; o[4 + j] = (bf16)c[j]; }
    *(bf16x8*)(dst + (size_t)m * (CD * CDA) + li) = o;
}

// ---------------------------------------------------------------------------
// GEMM: C = A[M,K] * W[N,K]^T + bias[N].  W is pre-converted bf16.
// AMODE 0: A fp32 (reg-convert staging, swizzled ds_writes).
// AMODE 1: A bf16 (global_load_lds, pre-swizzled source).
// B always staged via global_load_lds (pre-swizzled source).
// LDS layout both tiles: row stride 128B, 16B slot s holds K-block s^(row&7)
// (verified conflict-free read pattern, attn r6: SQ_LDS_BANK_CONFLICT == 0).
// OMODE 0: C[M,N] bf16.  1: C[M,N] f32.  2: C^T[N,CM] bf16 with within-64
// column permutation cp() on M (V^T for attention PV A-frag order).
// ---------------------------------------------------------------------------
template <int AMODE, int OMODE>
__global__ __launch_bounds__(256) void gemm_nt_bias(
    const void* __restrict__ Ap, const bf16* __restrict__ W,
    const float* __restrict__ bias, void* __restrict__ Cp,
    int M, int N, int K)
{
    __shared__ __align__(16) char smem[32768];
    char* As = smem;
    char* Bs = smem + 16384;

    const int t = threadIdx.x;
    const int lane = t & 63;
    const int wid = t >> 6;
    const int wr = wid >> 1, wc = wid & 1;
    const int l15 = lane & 15, lg = lane >> 4;
    const int m0 = blockIdx.x * 128;
    const int n0 = blockIdx.y * 128;

    f32x4 acc[4][4] = {};

    for (int k0 = 0; k0 < K; k0 += 64) {
        // ---- stage A tile 128x64 ----
        if (AMODE == 0) {
            const float* A = (const float*)Ap;
#pragma unroll
            for (int i = 0; i < 8; ++i) {
                int chunk = t + i * 256;
                int row = chunk >> 4, c4 = (chunk & 15) * 4;
                f32x4 v = *(const f32x4*)(A + (size_t)(m0 + row) * K + k0 + c4);
                bf16x4 o;
#pragma unroll
                for (int jj = 0; jj < 4; ++jj) o[jj] = (bf16)v[jj];
                *(bf16x4*)(As + row * 128 + (((c4 >> 3) ^ (row & 7)) << 4) +
                           ((c4 & 4) << 1)) = o;
            }
        } else {
            const bf16* A = (const bf16*)Ap;
#pragma unroll
            for (int i = 0; i < 4; ++i) {
                int chunk = t + i * 256;
                int row = chunk >> 3, slot = chunk & 7;
                const bf16* src = A + (size_t)(m0 + row) * K + k0 + ((slot ^ (row & 7)) << 3);
                __builtin_amdgcn_global_load_lds(
                    (const __attribute__((address_space(1))) void*)src,
                    (__attribute__((address_space(3))) void*)(As + ((i * 256 + wid * 64) << 4)),
                    16, 0, 0);
            }
        }
        // ---- stage B tile 128x64 via glds ----
#pragma unroll
        for (int i = 0; i < 4; ++i) {
            int chunk = t + i * 256;
            int row = chunk >> 3, slot = chunk & 7;
            const bf16* src = W + (size_t)(n0 + row) * K + k0 + ((slot ^ (row & 7)) << 3);
            __builtin_amdgcn_global_load_lds(
                (const __attribute__((address_space(1))) void*)src,
                (__attribute__((address_space(3))) void*)(Bs + ((i * 256 + wid * 64) << 4)),
                16, 0, 0);
        }
        __syncthreads();  // drains glds (vmcnt0 in barrier)

#pragma unroll
        for (int kk = 0; kk < 64; kk += 32) {
            bf16x8 af[4], bfv[4];
#pragma unroll
            for (int mi = 0; mi < 4; ++mi) {
                int row = wr * 64 + mi * 16 + l15;
                af[mi] = *(const bf16x8*)(As + row * 128 +
                                          ((((kk >> 3) + lg) ^ (row & 7)) << 4));
            }
#pragma unroll
            for (int ni = 0; ni < 4; ++ni) {
                int row = wc * 64 + ni * 16 + l15;
                bfv[ni] = *(const bf16x8*)(Bs + row * 128 +
                                           ((((kk >> 3) + lg) ^ (row & 7)) << 4));
            }
#pragma unroll
            for (int mi = 0; mi < 4; ++mi)
#pragma unroll
                for (int ni = 0; ni < 4; ++ni)
                    acc[mi][ni] = MFMA_BF16(af[mi], bfv[ni], acc[mi][ni]);
        }
        __syncthreads();  // protect tiles before next stage overwrites
    }

    if (OMODE == 2) {
        // C^T with permuted columns: (m,n) -> C[n][(m&~63) | cp(m&63)]
        bf16* C = (bf16*)Cp;
        const int mblock = m0 + wr * 64;
#pragma unroll
        for (int ni = 0; ni < 4; ++ni) {
            int n = n0 + wc * 64 + ni * 16 + l15;
            float bv = bias[n];
#pragma unroll
            for (int mi = 0; mi < 4; ++mi) {
                int s = mi * 16 + lg * 4;  // s&3 == 0
                int cps = (s & 32) | ((s & 12) << 1) | ((s & 16) >> 2);
                bf16x4 o;
#pragma unroll
                for (int r = 0; r < 4; ++r) o[r] = (bf16)(acc[mi][ni][r] + bv);
                *(bf16x4*)(C + (size_t)n * CM + mblock + cps) = o;
            }
        }
    } else {
#pragma unroll
        for (int ni = 0; ni < 4; ++ni) {
            int col = n0 + wc * 64 + ni * 16 + l15;
            float bv = bias[col];
#pragma unroll
            for (int mi = 0; mi < 4; ++mi) {
#pragma unroll
                for (int r = 0; r < 4; ++r) {
                    int row = m0 + wr * 64 + mi * 16 + lg * 4 + r;
                    float val = acc[mi][ni][r] + bv;
                    if (OMODE == 1)
                        ((float*)Cp)[(size_t)row * N + col] = val;
                    else
                        ((bf16*)Cp)[(size_t)row * N + col] = (bf16)val;
                }
            }
        }
    }
}

// ---------------------------------------------------------------------------
// Flash attention. 512 threads = 8 waves, 256 q-rows/block, XCD-swizzled grid.
// K and V^T staged via double-buffered global_load_lds (src pre-swizzled).
// Swapped QK^T keeps S^T in regs; scale folded into Q registers (x SC*log2e);
// static-max shift AND mask folded into the MFMA C-init (-M2 or -1e30), so
// the per-score path is exp2 only. P feeds PV A-operand directly (key order
// matched by xvT's cp() permutation). Row sums via ones-column MFMA.
// ---------------------------------------------------------------------------
__global__ __launch_bounds__(512, 4) void attn_kernel(
    const bf16* __restrict__ xq, const bf16* __restrict__ xk,
    const bf16* __restrict__ xvT, const int* __restrict__ mask,
    bf16* __restrict__ out)
{
    __shared__ __align__(16) char smem[32768];

    const int t = threadIdx.x;
    const int lane = t & 63;
    const int wid = t >> 6;                    // 0..7
    const int l15 = lane & 15, lg = lane >> 4;
    // XCD-aware decode: all 8 q-tiles of a bh share id%8 (same XCD)
    const int g = blockIdx.x;
    const int j = g >> 3;
    const int bh = (g & 7) * 8 + (j & 7);
    const int qt = j >> 3;
    const int b = bh >> 4, h = bh & 15;
    const int q0 = qt * 256;
    constexpr float SCL = 0.125f * 1.44269504088896340736f;  // folded into Q
    constexpr float M2 = 12.0f * SCL;                        // static softmax shift

    // per-lane staging sources (16B each; LDS dest is wave-uniform + lane*16)
    const int sub = lane >> 3;
    const int sb  = (lane & 7) ^ sub;
    const bf16* kbase = xk + (size_t)(b * CS + wid * 8 + sub) * CDA + h * 64 + sb * 8;
    const bf16* vbase = xvT + (size_t)(h * 64 + wid * 8 + sub) * CM + b * CS + sb * 8;

#define STAGE(bufi, ktt)                                                           \
    {                                                                              \
        char* Kd = smem + (bufi) * 16384 + wid * 1024;                             \
        char* Vd = smem + (bufi) * 16384 + 8192 + wid * 1024;                      \
        __builtin_amdgcn_global_load_lds(                                          \
            (const __attribute__((address_space(1))) void*)(kbase + (size_t)(ktt) * 64 * CDA), \
            (__attribute__((address_space(3))) void*)Kd, 16, 0, 0);                \
        __builtin_amdgcn_global_load_lds(                                          \
            (const __attribute__((address_space(1))) void*)(vbase + (ktt) * 64),   \
            (__attribute__((address_space(3))) void*)Vd, 16, 0, 0);                \
    }

    // ---- Q fragments: global -> registers once, pre-scaled by SCL ----
    bf16x8 aq[2][2];
#pragma unroll
    for (int mi = 0; mi < 2; ++mi)
#pragma unroll
        for (int kh = 0; kh < 2; ++kh) {
            bf16x8 v = *(const bf16x8*)(xq +
                (size_t)(b * CS + q0 + wid * 32 + mi * 16 + l15) * CDA + h * 64 + kh * 32 + lg * 8);
#pragma unroll
            for (int jj = 0; jj < 8; ++jj) v[jj] = (bf16)((float)v[jj] * SCL);
            aq[mi][kh] = v;
        }

    // ---- ones-column B-frag for row sums ----
    bf16x8 onescol;
    {
        bf16 fv = (l15 == 0) ? (bf16)1.0f : (bf16)0.0f;
#pragma unroll
        for (int jj = 0; jj < 8; ++jj) onescol[jj] = fv;
    }

    f32x4 accO[2][5] = {};

    STAGE(0, 0);
    __syncthreads();

    for (int kt = 0; kt < NT; ++kt) {
        const int cur = kt & 1;
        char* Ksb = smem + cur * 16384;
        char* Vtb = Ksb + 8192;

        // mask -> C-init bias (loaded before STAGE so its waitcnt leaves
        // the prefetch glds in flight)
        f32x4 mb[4];
#pragma unroll
        for (int ni = 0; ni < 4; ++ni) {
            i32x4 mk = *(const i32x4*)(mask + b * CS + kt * 64 + ni * 16 + lg * 4);
#pragma unroll
            for (int r = 0; r < 4; ++r)
                mb[ni][r] = (mk[r] == 0) ? -1.0e30f : -M2;
        }

        if (kt + 1 < NT) STAGE(cur ^ 1, kt + 1);

        // ---- swapped QK^T: sT[ni][mi] = S^T[key 16][qrow 16], C-init = bias ----
        f32x4 sT[4][2];
#pragma unroll
        for (int ni = 0; ni < 4; ++ni) { sT[ni][0] = mb[ni]; sT[ni][1] = mb[ni]; }
#pragma unroll
        for (int kh = 0; kh < 2; ++kh) {
            bf16x8 bk[4];
#pragma unroll
            for (int ni = 0; ni < 4; ++ni) {
                int key = ni * 16 + l15;
                bk[ni] = *(const bf16x8*)(Ksb + key * 128 +
                                          ((kh * 64 + lg * 16) ^ ((key & 7) << 4)));
            }
#pragma unroll
            for (int ni = 0; ni < 4; ++ni)
#pragma unroll
                for (int mi = 0; mi < 2; ++mi)
                    sT[ni][mi] = MFMA_BF16(bk[ni], aq[mi][kh], sT[ni][mi]);
        }

        // ---- softmax: per-score path is exp2 only ----
#pragma unroll
        for (int ni = 0; ni < 4; ++ni)
#pragma unroll
            for (int mi = 0; mi < 2; ++mi)
#pragma unroll
                for (int r = 0; r < 4; ++r)
                    sT[ni][mi][r] = exp2f(sT[ni][mi][r]);

        // ---- pack P into PV A-frags (in-register; order matches xvT perm) ----
        bf16x8 ap[2][2];
#pragma unroll
        for (int kks = 0; kks < 2; ++kks)
#pragma unroll
            for (int mi = 0; mi < 2; ++mi)
#pragma unroll
                for (int r = 0; r < 4; ++r) {
                    ap[kks][mi][r]     = (bf16)sT[2 * kks][mi][r];
                    ap[kks][mi][4 + r] = (bf16)sT[2 * kks + 1][mi][r];
                }

        // ---- PV (+ in-register ones column di=4) ----
#pragma unroll
        for (int kks = 0; kks < 2; ++kks) {
            bf16x8 bv[4];
#pragma unroll
            for (int di = 0; di < 4; ++di) {
                int d = di * 16 + l15;
                bv[di] = *(const bf16x8*)(Vtb + d * 128 +
                                          ((kks * 64 + lg * 16) ^ ((d & 7) << 4)));
            }
#pragma unroll
            for (int mi = 0; mi < 2; ++mi) {
#pragma unroll
                for (int di = 0; di < 4; ++di)
                    accO[mi][di] = MFMA_BF16(ap[kks][mi], bv[di], accO[mi][di]);
                accO[mi][4] = MFMA_BF16(ap[kks][mi], onescol, accO[mi][4]);
            }
        }

        __syncthreads();  // drains this iter's glds; orders cur-buffer reuse
    }
#undef STAGE

    // ---- epilogue: divide by sum, per-wave staging in smem, b128 stores ----
    char* Ob = smem + wid * 2048;  // 16 rows x 128B per wave
#pragma unroll
    for (int mi = 0; mi < 2; ++mi) {
#pragma unroll
        for (int r = 0; r < 4; ++r) {
            float lsum = __shfl(accO[mi][4][r], lane & 48);
            float inv = 1.0f / lsum;
            int qr = lg * 4 + r;
#pragma unroll
            for (int di = 0; di < 4; ++di)
                *(bf16*)(Ob + qr * 128 + (((di * 16 + l15) * 2) ^ ((qr & 7) << 4))) =
                    (bf16)(accO[mi][di][r] * inv);
        }
        __builtin_amdgcn_sched_barrier(0);  // keep stage-writes before readback
#pragma unroll
        for (int i = 0; i < 2; ++i) {
            int rr = i * 8 + (lane >> 3);
            int ch = lane & 7;
            bf16x8 o = *(const bf16x8*)(Ob + rr * 128 + ((ch * 16) ^ ((rr & 7) << 4)));
            *(bf16x8*)(out + (size_t)(b * CS + q0 + wid * 32 + mi * 16 + rr) * CDA +
                       h * 64 + ch * 8) = o;
        }
        __builtin_amdgcn_sched_barrier(0);  // keep mi=1 writes after mi=0 reads
    }
}

// ---------------------------------------------------------------------------
extern "C" void kernel_launch(void* const* d_in, const int* in_sizes, int n_in,
                              void* d_out, int out_size, void* d_ws, size_t ws_size,
                              hipStream_t stream)
{
    const float* q   = (const float*)d_in[0];
    const float* k   = (const float*)d_in[1];
    const float* v   = (const float*)d_in[2];
    const int*   msk = (const int*)d_in[3];
    const float* w_q = (const float*)d_in[4];
    const float* b_q = (const float*)d_in[5];
    const float* w_k = (const float*)d_in[6];
    const float* b_k = (const float*)d_in[7];
    const float* w_v = (const float*)d_in[8];
    const float* b_v = (const float*)d_in[9];
    const float* w_o = (const float*)d_in[10];
    const float* b_o = (const float*)d_in[11];

    bf16* xq  = (bf16*)d_ws;
    bf16* xk  = xq + (size_t)CM * CDA;
    bf16* xvT = xk + (size_t)CM * CDA;   // [DA][CM], keys permuted within 64-blocks
    bf16* at  = xvT + (size_t)CM * CDA;
    bf16* wb  = at + (size_t)CM * CDA;   // 4 x 1M bf16 weights

    cvt_w4<<<dim3(2048), 256, 0, stream>>>(w_q, w_k, w_v, w_o, wb);

    const size_t WSZ = (size_t)CD * CDA;
    dim3 gp(CM / 128, CDA / 128);
    gemm_nt_bias<0, 0><<<gp, 256, 0, stream>>>((const void*)q, wb,           b_q, (void*)xq,  CM, CDA, CD);
    gemm_nt_bias<0, 0><<<gp, 256, 0, stream>>>((const void*)k, wb + WSZ,     b_k, (void*)xk,  CM, CDA, CD);
    gemm_nt_bias<0, 2><<<gp, 256, 0, stream>>>((const void*)v, wb + 2 * WSZ, b_v, (void*)xvT, CM, CDA, CD);

    attn_kernel<<<dim3(512), 512, 0, stream>>>(xq, xk, xvT, msk, at);

    gemm_nt_bias<1, 1><<<dim3(CM / 128, CD / 128), 256, 0, stream>>>(
        (const void*)at, wb + 3 * WSZ, b_o, d_out, CM, CD, CDA);
}